// Round 1
// baseline (2043.563 us; speedup 1.0000x reference)
//
#include <hip/hip_runtime.h>

#define NN 100000     // nodes
#define NE 1600000    // edges
#define FIN 100
#define D 64
#define NCONV 4
#define NG 500

// ---------------- degree / norm ----------------
__global__ void k_deg(const int* __restrict__ col, const float* __restrict__ ew,
                      float* __restrict__ deg) {
    int e = blockIdx.x * blockDim.x + threadIdx.x;
    if (e < NE) atomicAdd(&deg[col[e]], ew[e]);
}

__global__ void k_dis(float* __restrict__ deg) {
    int i = blockIdx.x * blockDim.x + threadIdx.x;
    if (i < NN) {
        float d = deg[i];
        deg[i] = (d > 0.f) ? (1.0f / sqrtf(d)) : 0.f;
    }
}

__global__ void k_norm(const int* __restrict__ row, const int* __restrict__ col,
                       const float* __restrict__ ew, const float* __restrict__ dis,
                       float* __restrict__ nrm) {
    int e = blockIdx.x * blockDim.x + threadIdx.x;
    if (e < NE) nrm[e] = dis[row[e]] * ew[e] * dis[col[e]];
}

// ---------------- lin0: out = relu(x @ W0 + b0), x [N,100], W0 [100,64] ----------------
__global__ __launch_bounds__(256) void k_lin0(const float* __restrict__ x,
                                              const float* __restrict__ w,
                                              const float* __restrict__ b,
                                              float* __restrict__ out) {
    __shared__ float ws[FIN * D];     // 25.6 KB
    __shared__ float xs[4][FIN];      // 1.6 KB
    int t = threadIdx.x;
    for (int i = t; i < FIN * D; i += 256) ws[i] = w[i];
    int r0 = blockIdx.x * 4;
    for (int i = t; i < 4 * FIN; i += 256) {
        int rr = r0 + i / FIN, kk = i % FIN;
        xs[i / FIN][kk] = (rr < NN) ? x[rr * FIN + kk] : 0.f;
    }
    __syncthreads();
    int g = t >> 6, lane = t & 63;
    int r = r0 + g;
    if (r < NN) {
        float acc = b[lane];
        #pragma unroll
        for (int k = 0; k < FIN; ++k) acc += xs[g][k] * ws[k * D + lane];
        out[r * D + lane] = fmaxf(acc, 0.f);
    }
}

// ---------------- scatter: agg[col] += src[row] * norm ----------------
__global__ __launch_bounds__(256) void k_scatter(const int* __restrict__ row,
                                                 const int* __restrict__ col,
                                                 const float* __restrict__ nrm,
                                                 const float* __restrict__ src,
                                                 float* __restrict__ agg) {
    int e = blockIdx.x * (blockDim.x >> 6) + (threadIdx.x >> 6);
    if (e >= NE) return;
    int lane = threadIdx.x & 63;
    int r = row[e], c = col[e];
    float w = nrm[e];
    float v = src[r * D + lane] * w;
    atomicAdd(&agg[c * D + lane], v);
}

// ---------------- out = relu(a @ W + b), a [N,64], W [64,64] ----------------
__global__ __launch_bounds__(256) void k_mm_relu(const float* __restrict__ a,
                                                 const float* __restrict__ w,
                                                 const float* __restrict__ b,
                                                 float* __restrict__ out) {
    __shared__ float ws[D * D];       // 16 KB
    __shared__ float as[4][D];
    int t = threadIdx.x;
    for (int i = t; i < D * D; i += 256) ws[i] = w[i];
    int r0 = blockIdx.x * 4;
    for (int i = t; i < 4 * D; i += 256) {
        int rr = r0 + (i >> 6);
        as[i >> 6][i & 63] = (rr < NN) ? a[rr * D + (i & 63)] : 0.f;
    }
    __syncthreads();
    int g = t >> 6, lane = t & 63;
    int r = r0 + g;
    if (r < NN) {
        float acc = b[lane];
        #pragma unroll
        for (int k = 0; k < D; ++k) acc += as[g][k] * ws[k * D + lane];
        out[r * D + lane] = fmaxf(acc, 0.f);
    }
}

// ---------------- global mean pool (accumulate) ----------------
__global__ void k_pool(const float* __restrict__ src, const int* __restrict__ batch,
                       float* __restrict__ pooled, float* __restrict__ cnt) {
    int t = blockIdx.x * blockDim.x + threadIdx.x;
    int i = t >> 6, lane = t & 63;
    if (i < NN) {
        int g = batch[i];
        atomicAdd(&pooled[g * D + lane], src[i * D + lane]);
        if (lane == 0) atomicAdd(&cnt[g], 1.0f);
    }
}

// ---------------- MLP head: one block per graph ----------------
__global__ __launch_bounds__(64) void k_head(const float* __restrict__ pooled,
                                             const float* __restrict__ cnt,
                                             const float* __restrict__ lin1_w,
                                             const float* __restrict__ lin1_b,
                                             const float* __restrict__ fc_w,
                                             const float* __restrict__ fc_b,
                                             const float* __restrict__ lin2_w,
                                             const float* __restrict__ lin2_b,
                                             float* __restrict__ out) {
    __shared__ float buf0[D], buf1[D];
    int g = blockIdx.x, d = threadIdx.x;
    float c = fmaxf(cnt[g], 1.0f);
    buf0[d] = pooled[g * D + d] / c;
    __syncthreads();
    // lin1
    float acc = lin1_b[d];
    #pragma unroll
    for (int k = 0; k < D; ++k) acc += buf0[k] * lin1_w[k * D + d];
    buf1[d] = fmaxf(acc, 0.f);
    __syncthreads();
    // fc0
    acc = fc_b[d];
    #pragma unroll
    for (int k = 0; k < D; ++k) acc += buf1[k] * fc_w[k * D + d];
    buf0[d] = fmaxf(acc, 0.f);
    __syncthreads();
    // fc1
    acc = fc_b[D + d];
    #pragma unroll
    for (int k = 0; k < D; ++k) acc += buf0[k] * fc_w[D * D + k * D + d];
    buf1[d] = fmaxf(acc, 0.f);
    __syncthreads();
    // lin2 -> scalar
    float v = buf1[d] * lin2_w[d];
    #pragma unroll
    for (int off = 32; off; off >>= 1) v += __shfl_down(v, off);
    if (d == 0) out[g] = v + lin2_b[0];
}

extern "C" void kernel_launch(void* const* d_in, const int* in_sizes, int n_in,
                              void* d_out, int out_size, void* d_ws, size_t ws_size,
                              hipStream_t stream) {
    const float* x      = (const float*)d_in[0];
    const int*   ei     = (const int*)  d_in[1];
    const float* ew     = (const float*)d_in[2];
    const int*   batch  = (const int*)  d_in[3];
    const float* lin0_w = (const float*)d_in[4];
    const float* lin0_b = (const float*)d_in[5];
    const float* conv_w = (const float*)d_in[6];
    const float* conv_b = (const float*)d_in[7];
    const float* lin1_w = (const float*)d_in[8];
    const float* lin1_b = (const float*)d_in[9];
    const float* fc_w   = (const float*)d_in[10];
    const float* fc_b   = (const float*)d_in[11];
    const float* lin2_w = (const float*)d_in[12];
    const float* lin2_b = (const float*)d_in[13];
    float* out = (float*)d_out;

    const int* rowv = ei;
    const int* colv = ei + NE;

    float* bufA   = (float*)d_ws;          // N*D
    float* bufB   = bufA + (size_t)NN * D; // N*D
    float* normv  = bufB + (size_t)NN * D; // E
    float* deg    = normv + NE;            // N  (becomes dis in-place)
    float* pooled = deg + NN;              // G*D
    float* cnt    = pooled + NG * D;       // G

    hipMemsetAsync(deg, 0, NN * sizeof(float), stream);
    k_deg<<<(NE + 255) / 256, 256, 0, stream>>>(colv, ew, deg);
    k_dis<<<(NN + 255) / 256, 256, 0, stream>>>(deg);
    k_norm<<<(NE + 255) / 256, 256, 0, stream>>>(rowv, colv, ew, deg, normv);

    k_lin0<<<(NN + 3) / 4, 256, 0, stream>>>(x, lin0_w, lin0_b, bufA);

    for (int i = 0; i < NCONV; ++i) {
        hipMemsetAsync(bufB, 0, (size_t)NN * D * sizeof(float), stream);
        k_scatter<<<(NE + 3) / 4, 256, 0, stream>>>(rowv, colv, normv, bufA, bufB);
        k_mm_relu<<<(NN + 3) / 4, 256, 0, stream>>>(bufB, conv_w + i * D * D,
                                                    conv_b + i * D, bufA);
    }

    hipMemsetAsync(pooled, 0, (NG * D + NG) * sizeof(float), stream);
    k_pool<<<((size_t)NN * 64 + 255) / 256, 256, 0, stream>>>(bufA, batch, pooled, cnt);
    k_head<<<NG, 64, 0, stream>>>(pooled, cnt, lin1_w, lin1_b, fc_w, fc_b,
                                  lin2_w, lin2_b, out);
}

// Round 2
// 1085.344 us; speedup vs baseline: 1.8829x; 1.8829x over previous
//
#include <hip/hip_runtime.h>

#define NN 100000     // nodes
#define NE 1600000    // edges
#define FIN 100
#define D 64
#define NCONV 4
#define NG 500
#define SCAN_T 512
#define NB0 ((NN + SCAN_T - 1) / SCAN_T)   // 196

// ---------------- degree (float) + count (int) histogram over dst ----------------
__global__ void k_degcnt(const int* __restrict__ col, const float* __restrict__ ew,
                         float* __restrict__ deg, int* __restrict__ counts) {
    int e = blockIdx.x * blockDim.x + threadIdx.x;
    if (e < NE) {
        int c = col[e];
        atomicAdd(&deg[c], ew[e]);
        atomicAdd(&counts[c], 1);
    }
}

__global__ void k_dis(float* __restrict__ deg) {
    int i = blockIdx.x * blockDim.x + threadIdx.x;
    if (i < NN) {
        float d = deg[i];
        deg[i] = (d > 0.f) ? (1.0f / sqrtf(d)) : 0.f;   // deg -> deg^{-1/2}
    }
}

// ---------------- two-level exclusive scan of counts -> rowstart ----------------
__global__ __launch_bounds__(SCAN_T) void k_scan1(const int* __restrict__ counts,
                                                  int* __restrict__ rowstart,
                                                  int* __restrict__ bsums) {
    __shared__ int sh[SCAN_T];
    int t = threadIdx.x, i = blockIdx.x * SCAN_T + t;
    int v = (i < NN) ? counts[i] : 0;
    sh[t] = v;
    __syncthreads();
    for (int off = 1; off < SCAN_T; off <<= 1) {
        int u = (t >= off) ? sh[t - off] : 0;
        __syncthreads();
        sh[t] += u;
        __syncthreads();
    }
    if (i < NN) rowstart[i] = sh[t] - v;      // exclusive
    if (t == SCAN_T - 1) bsums[blockIdx.x] = sh[t];
}

__global__ __launch_bounds__(256) void k_scan2(int* __restrict__ bsums) {
    __shared__ int sh[256];
    int t = threadIdx.x;
    int v = (t < NB0) ? bsums[t] : 0;
    sh[t] = v;
    __syncthreads();
    for (int off = 1; off < 256; off <<= 1) {
        int u = (t >= off) ? sh[t - off] : 0;
        __syncthreads();
        sh[t] += u;
        __syncthreads();
    }
    if (t < NB0) bsums[t] = sh[t] - v;        // exclusive over block sums
}

__global__ __launch_bounds__(SCAN_T) void k_scan3(int* __restrict__ rowstart,
                                                  const int* __restrict__ bsums) {
    int i = blockIdx.x * SCAN_T + threadIdx.x;
    if (i < NN) rowstart[i] += bsums[blockIdx.x];
    if (i == 0) rowstart[NN] = NE;
}

// ---------------- CSR fill: slot = rowstart[c] + rank; payload = (src, norm) ----
__global__ void k_fill(const int* __restrict__ row, const int* __restrict__ col,
                       const float* __restrict__ ew, const float* __restrict__ dis,
                       const int* __restrict__ rowstart, int* __restrict__ cursor,
                       int* __restrict__ csr_src, float* __restrict__ csr_w) {
    int e = blockIdx.x * blockDim.x + threadIdx.x;
    if (e >= NE) return;
    int r = row[e], c = col[e];
    int slot = rowstart[c] + atomicAdd(&cursor[c], 1);
    csr_src[slot] = r;
    csr_w[slot] = dis[r] * ew[e] * dis[c];
}

// ---------------- lin0: out = relu(x @ W0 + b0), x [N,100], W0 [100,64] ----------
__global__ __launch_bounds__(256) void k_lin0(const float* __restrict__ x,
                                              const float* __restrict__ w,
                                              const float* __restrict__ b,
                                              float* __restrict__ out) {
    __shared__ float ws[FIN * D];     // 25.6 KB
    __shared__ float xs[4][FIN];
    int t = threadIdx.x;
    for (int i = t; i < FIN * D; i += 256) ws[i] = w[i];
    int r0 = blockIdx.x * 4;
    for (int i = t; i < 4 * FIN; i += 256) {
        int rr = r0 + i / FIN, kk = i % FIN;
        xs[i / FIN][kk] = (rr < NN) ? x[rr * FIN + kk] : 0.f;
    }
    __syncthreads();
    int g = t >> 6, lane = t & 63;
    int r = r0 + g;
    if (r < NN) {
        float acc = b[lane];
        #pragma unroll
        for (int k = 0; k < FIN; ++k) acc += xs[g][k] * ws[k * D + lane];
        out[r * D + lane] = fmaxf(acc, 0.f);
    }
}

// ---------------- fused conv: gather-aggregate (CSR) + 64x64 matmul + bias + relu
// one wave per dst node; lane = feature index; final layer pools via atomics.
template <bool POOL>
__global__ __launch_bounds__(256) void k_conv(const float* __restrict__ src,
                                              const int* __restrict__ rowstart,
                                              const int* __restrict__ csr_src,
                                              const float* __restrict__ csr_w,
                                              const float* __restrict__ w,
                                              const float* __restrict__ bias,
                                              const int* __restrict__ batch,
                                              float* __restrict__ dst) {
    __shared__ float ws[D * D];       // 16 KB
    int t = threadIdx.x;
    for (int i = t; i < D * D; i += 256) ws[i] = w[i];
    __syncthreads();
    int lane = t & 63;
    int node = blockIdx.x * 4 + (t >> 6);          // NN % 4 == 0, always valid
    int e0 = rowstart[node], e1 = rowstart[node + 1];
    float acc = 0.f;
    for (int base = e0; base < e1; base += 64) {
        int n = e1 - base;
        if (n > 64) n = 64;
        int s = 0;
        float wv = 0.f;
        if (lane < n) { s = csr_src[base + lane]; wv = csr_w[base + lane]; }
        for (int k = 0; k < n; ++k) {
            int sk = __shfl(s, k);
            float wk = __shfl(wv, k);
            acc = fmaf(src[sk * D + lane], wk, acc);   // coalesced 256B row gather
        }
    }
    // matmul: o[lane] = bias[lane] + sum_k acc_row[k] * W[k][lane]
    float o = bias[lane];
    #pragma unroll
    for (int k = 0; k < D; ++k) o = fmaf(__shfl(acc, k), ws[k * D + lane], o);
    o = fmaxf(o, 0.f);
    if (POOL) atomicAdd(&dst[batch[node] * D + lane], o);
    else      dst[node * D + lane] = o;
}

// ---------------- per-graph node counts ----------------
__global__ void k_cnt(const int* __restrict__ batch, float* __restrict__ cnt) {
    int i = blockIdx.x * blockDim.x + threadIdx.x;
    if (i < NN) atomicAdd(&cnt[batch[i]], 1.f);
}

// ---------------- MLP head: one block per graph ----------------
__global__ __launch_bounds__(64) void k_head(const float* __restrict__ pooled,
                                             const float* __restrict__ cnt,
                                             const float* __restrict__ lin1_w,
                                             const float* __restrict__ lin1_b,
                                             const float* __restrict__ fc_w,
                                             const float* __restrict__ fc_b,
                                             const float* __restrict__ lin2_w,
                                             const float* __restrict__ lin2_b,
                                             float* __restrict__ out) {
    __shared__ float buf0[D], buf1[D];
    int g = blockIdx.x, d = threadIdx.x;
    float c = fmaxf(cnt[g], 1.0f);
    buf0[d] = pooled[g * D + d] / c;
    __syncthreads();
    float acc = lin1_b[d];
    #pragma unroll
    for (int k = 0; k < D; ++k) acc += buf0[k] * lin1_w[k * D + d];
    buf1[d] = fmaxf(acc, 0.f);
    __syncthreads();
    acc = fc_b[d];
    #pragma unroll
    for (int k = 0; k < D; ++k) acc += buf1[k] * fc_w[k * D + d];
    buf0[d] = fmaxf(acc, 0.f);
    __syncthreads();
    acc = fc_b[D + d];
    #pragma unroll
    for (int k = 0; k < D; ++k) acc += buf0[k] * fc_w[D * D + k * D + d];
    buf1[d] = fmaxf(acc, 0.f);
    __syncthreads();
    float v = buf1[d] * lin2_w[d];
    #pragma unroll
    for (int off = 32; off; off >>= 1) v += __shfl_down(v, off);
    if (d == 0) out[g] = v + lin2_b[0];
}

extern "C" void kernel_launch(void* const* d_in, const int* in_sizes, int n_in,
                              void* d_out, int out_size, void* d_ws, size_t ws_size,
                              hipStream_t stream) {
    const float* x      = (const float*)d_in[0];
    const int*   ei     = (const int*)  d_in[1];
    const float* ew     = (const float*)d_in[2];
    const int*   batch  = (const int*)  d_in[3];
    const float* lin0_w = (const float*)d_in[4];
    const float* lin0_b = (const float*)d_in[5];
    const float* conv_w = (const float*)d_in[6];
    const float* conv_b = (const float*)d_in[7];
    const float* lin1_w = (const float*)d_in[8];
    const float* lin1_b = (const float*)d_in[9];
    const float* fc_w   = (const float*)d_in[10];
    const float* fc_b   = (const float*)d_in[11];
    const float* lin2_w = (const float*)d_in[12];
    const float* lin2_b = (const float*)d_in[13];
    float* out = (float*)d_out;

    const int* rowv = ei;
    const int* colv = ei + NE;

    // workspace layout (~66 MB)
    float* bufA     = (float*)d_ws;                 // N*D
    float* bufB     = bufA + (size_t)NN * D;        // N*D
    int*   csr_src  = (int*)(bufB + (size_t)NN * D);// E
    float* csr_w    = (float*)(csr_src + NE);       // E
    int*   rowstart = (int*)(csr_w + NE);           // N+1
    float* deg      = (float*)(rowstart + NN + 1);  // N (becomes dis in place)
    int*   counts   = (int*)(deg + NN);             // N
    int*   cursor   = counts + NN;                  // N
    int*   bsums    = cursor + NN;                  // 256
    float* pooled   = (float*)(bsums + 256);        // G*D
    float* cnt      = pooled + NG * D;              // G

    hipMemsetAsync(deg, 0, 3 * NN * sizeof(float), stream);          // deg+counts+cursor
    hipMemsetAsync(pooled, 0, (NG * D + NG) * sizeof(float), stream);

    k_degcnt<<<(NE + 255) / 256, 256, 0, stream>>>(colv, ew, deg, counts);
    k_dis<<<(NN + 255) / 256, 256, 0, stream>>>(deg);
    k_scan1<<<NB0, SCAN_T, 0, stream>>>(counts, rowstart, bsums);
    k_scan2<<<1, 256, 0, stream>>>(bsums);
    k_scan3<<<NB0, SCAN_T, 0, stream>>>(rowstart, bsums);
    k_fill<<<(NE + 255) / 256, 256, 0, stream>>>(rowv, colv, ew, deg, rowstart,
                                                 cursor, csr_src, csr_w);

    k_lin0<<<NN / 4, 256, 0, stream>>>(x, lin0_w, lin0_b, bufA);

    k_conv<false><<<NN / 4, 256, 0, stream>>>(bufA, rowstart, csr_src, csr_w,
                                              conv_w + 0 * D * D, conv_b + 0 * D,
                                              nullptr, bufB);
    k_conv<false><<<NN / 4, 256, 0, stream>>>(bufB, rowstart, csr_src, csr_w,
                                              conv_w + 1 * D * D, conv_b + 1 * D,
                                              nullptr, bufA);
    k_conv<false><<<NN / 4, 256, 0, stream>>>(bufA, rowstart, csr_src, csr_w,
                                              conv_w + 2 * D * D, conv_b + 2 * D,
                                              nullptr, bufB);
    k_cnt<<<(NN + 255) / 256, 256, 0, stream>>>(batch, cnt);
    k_conv<true><<<NN / 4, 256, 0, stream>>>(bufB, rowstart, csr_src, csr_w,
                                             conv_w + 3 * D * D, conv_b + 3 * D,
                                             batch, pooled);

    k_head<<<NG, 64, 0, stream>>>(pooled, cnt, lin1_w, lin1_b, fc_w, fc_b,
                                  lin2_w, lin2_b, out);
}

// Round 3
// 860.645 us; speedup vs baseline: 2.3745x; 1.2611x over previous
//
#include <hip/hip_runtime.h>

#define NN 100000     // nodes
#define NE 1600000    // edges
#define FIN 100
#define D 64
#define NCONV 4
#define NG 500
#define SCAN_T 512
#define NB0 ((NN + SCAN_T - 1) / SCAN_T)   // 196

// ---------------- degree (float) + count (int) histogram over dst ----------------
__global__ void k_degcnt(const int* __restrict__ col, const float* __restrict__ ew,
                         float* __restrict__ deg, int* __restrict__ counts) {
    int e = blockIdx.x * blockDim.x + threadIdx.x;
    if (e < NE) {
        int c = col[e];
        atomicAdd(&deg[c], ew[e]);
        atomicAdd(&counts[c], 1);
    }
}

__global__ void k_dis(float* __restrict__ deg) {
    int i = blockIdx.x * blockDim.x + threadIdx.x;
    if (i < NN) {
        float d = deg[i];
        deg[i] = (d > 0.f) ? (1.0f / sqrtf(d)) : 0.f;   // deg -> deg^{-1/2}
    }
}

// ---------------- two-level exclusive scan of counts -> rowstart ----------------
__global__ __launch_bounds__(SCAN_T) void k_scan1(const int* __restrict__ counts,
                                                  int* __restrict__ rowstart,
                                                  int* __restrict__ bsums) {
    __shared__ int sh[SCAN_T];
    int t = threadIdx.x, i = blockIdx.x * SCAN_T + t;
    int v = (i < NN) ? counts[i] : 0;
    sh[t] = v;
    __syncthreads();
    for (int off = 1; off < SCAN_T; off <<= 1) {
        int u = (t >= off) ? sh[t - off] : 0;
        __syncthreads();
        sh[t] += u;
        __syncthreads();
    }
    if (i < NN) rowstart[i] = sh[t] - v;      // exclusive
    if (t == SCAN_T - 1) bsums[blockIdx.x] = sh[t];
}

__global__ __launch_bounds__(256) void k_scan2(int* __restrict__ bsums) {
    __shared__ int sh[256];
    int t = threadIdx.x;
    int v = (t < NB0) ? bsums[t] : 0;
    sh[t] = v;
    __syncthreads();
    for (int off = 1; off < 256; off <<= 1) {
        int u = (t >= off) ? sh[t - off] : 0;
        __syncthreads();
        sh[t] += u;
        __syncthreads();
    }
    if (t < NB0) bsums[t] = sh[t] - v;        // exclusive over block sums
}

__global__ __launch_bounds__(SCAN_T) void k_scan3(int* __restrict__ rowstart,
                                                  const int* __restrict__ bsums) {
    int i = blockIdx.x * SCAN_T + threadIdx.x;
    if (i < NN) rowstart[i] += bsums[blockIdx.x];
    if (i == 0) rowstart[NN] = NE;
}

// ---------------- CSR fill: slot = rowstart[c] + rank; payload = (src, norm) ----
__global__ void k_fill(const int* __restrict__ row, const int* __restrict__ col,
                       const float* __restrict__ ew, const float* __restrict__ dis,
                       const int* __restrict__ rowstart, int* __restrict__ cursor,
                       int2* __restrict__ csr) {
    int e = blockIdx.x * blockDim.x + threadIdx.x;
    if (e >= NE) return;
    int r = row[e], c = col[e];
    int slot = rowstart[c] + atomicAdd(&cursor[c], 1);
    float nw = dis[r] * ew[e] * dis[c];
    csr[slot] = make_int2(r, __float_as_int(nw));
}

// ---------------- lin0: out = relu(x @ W0 + b0), x [N,100], W0 [100,64] ----------
// 16 rows per block (4 waves x 4 rows), W staged once.
__global__ __launch_bounds__(256) void k_lin0(const float* __restrict__ x,
                                              const float* __restrict__ w,
                                              const float* __restrict__ b,
                                              float* __restrict__ out) {
    __shared__ float ws[FIN * D];     // 25.6 KB
    __shared__ float xs[16][FIN];     // 6.4 KB
    int t = threadIdx.x;
    for (int i = t; i < FIN * D; i += 256) ws[i] = w[i];
    int r0 = blockIdx.x * 16;
    for (int i = t; i < 16 * FIN; i += 256) {
        int rr = i / FIN, kk = i - rr * FIN;
        xs[rr][kk] = x[(r0 + rr) * FIN + kk];   // NN % 16 == 0
    }
    __syncthreads();
    int wave = t >> 6, lane = t & 63;
    float bv = b[lane];
    for (int ri = wave; ri < 16; ri += 4) {
        float acc = bv;
        #pragma unroll
        for (int k = 0; k < FIN; k += 4) {
            float4 xv = *reinterpret_cast<const float4*>(&xs[ri][k]);
            acc = fmaf(xv.x, ws[(k + 0) * D + lane], acc);
            acc = fmaf(xv.y, ws[(k + 1) * D + lane], acc);
            acc = fmaf(xv.z, ws[(k + 2) * D + lane], acc);
            acc = fmaf(xv.w, ws[(k + 3) * D + lane], acc);
        }
        out[(r0 + ri) * D + lane] = fmaxf(acc, 0.f);
    }
}

// ---------------- fused conv: CSR gather-aggregate + 64x64 matmul + bias + relu
// 16 nodes per block; one wave per node (4 nodes sequential per wave).
// Lane split: g = lane>>4 (edge subgroup), f = lane&15 (feature quad).
// 8 edges in flight per iteration (2x unroll of 4-wide edge groups).
template <bool POOL>
__global__ __launch_bounds__(256) void k_conv(const float* __restrict__ src,
                                              const int* __restrict__ rowstart,
                                              const int2* __restrict__ csr,
                                              const float* __restrict__ w,
                                              const float* __restrict__ bias,
                                              const int* __restrict__ batch,
                                              float* __restrict__ dst) {
    __shared__ float ws[D * D];       // 16 KB
    __shared__ float row_lds[4][D];   // 1 KB, per-wave slot
    int t = threadIdx.x;
    for (int i = t; i < D * D; i += 256) ws[i] = w[i];
    __syncthreads();
    int wave = t >> 6, lane = t & 63;
    int g = lane >> 4;       // 0..3 edge subgroup
    int f = lane & 15;       // feature quad: features f*4 .. f*4+3
    int node0 = blockIdx.x * 16;
    float bv = bias[lane];
    for (int ni = wave; ni < 16; ni += 4) {
        int node = node0 + ni;                   // NN % 16 == 0, always valid
        int e0 = rowstart[node], e1 = rowstart[node + 1];
        float4 acc = {0.f, 0.f, 0.f, 0.f};
        for (int base = e0; base < e1; base += 8) {
            int ea = base + g;
            int eb = base + 4 + g;
            if (ea < e1) {
                int2 p = csr[ea];
                float wv = __int_as_float(p.y);
                float4 v = *reinterpret_cast<const float4*>(&src[p.x * D + f * 4]);
                acc.x = fmaf(v.x, wv, acc.x);
                acc.y = fmaf(v.y, wv, acc.y);
                acc.z = fmaf(v.z, wv, acc.z);
                acc.w = fmaf(v.w, wv, acc.w);
            }
            if (eb < e1) {
                int2 p = csr[eb];
                float wv = __int_as_float(p.y);
                float4 v = *reinterpret_cast<const float4*>(&src[p.x * D + f * 4]);
                acc.x = fmaf(v.x, wv, acc.x);
                acc.y = fmaf(v.y, wv, acc.y);
                acc.z = fmaf(v.z, wv, acc.z);
                acc.w = fmaf(v.w, wv, acc.w);
            }
        }
        // reduce across the 4 edge subgroups (lanes f, f+16, f+32, f+48)
        acc.x += __shfl_xor(acc.x, 16); acc.y += __shfl_xor(acc.y, 16);
        acc.z += __shfl_xor(acc.z, 16); acc.w += __shfl_xor(acc.w, 16);
        acc.x += __shfl_xor(acc.x, 32); acc.y += __shfl_xor(acc.y, 32);
        acc.z += __shfl_xor(acc.z, 32); acc.w += __shfl_xor(acc.w, 32);
        if (g == 0) *reinterpret_cast<float4*>(&row_lds[wave][f * 4]) = acc;
        // matmul: o[lane] = bias + sum_k row[k] * W[k][lane]  (LDS broadcast reads)
        float o = bv;
        #pragma unroll
        for (int k = 0; k < D; k += 4) {
            float4 r = *reinterpret_cast<const float4*>(&row_lds[wave][k]);
            o = fmaf(r.x, ws[(k + 0) * D + lane], o);
            o = fmaf(r.y, ws[(k + 1) * D + lane], o);
            o = fmaf(r.z, ws[(k + 2) * D + lane], o);
            o = fmaf(r.w, ws[(k + 3) * D + lane], o);
        }
        o = fmaxf(o, 0.f);
        if (POOL) atomicAdd(&dst[batch[node] * D + lane], o);
        else      dst[node * D + lane] = o;
    }
}

// ---------------- per-graph node counts ----------------
__global__ void k_cnt(const int* __restrict__ batch, float* __restrict__ cnt) {
    int i = blockIdx.x * blockDim.x + threadIdx.x;
    if (i < NN) atomicAdd(&cnt[batch[i]], 1.f);
}

// ---------------- MLP head: one block per graph ----------------
__global__ __launch_bounds__(64) void k_head(const float* __restrict__ pooled,
                                             const float* __restrict__ cnt,
                                             const float* __restrict__ lin1_w,
                                             const float* __restrict__ lin1_b,
                                             const float* __restrict__ fc_w,
                                             const float* __restrict__ fc_b,
                                             const float* __restrict__ lin2_w,
                                             const float* __restrict__ lin2_b,
                                             float* __restrict__ out) {
    __shared__ float buf0[D], buf1[D];
    int g = blockIdx.x, d = threadIdx.x;
    float c = fmaxf(cnt[g], 1.0f);
    buf0[d] = pooled[g * D + d] / c;
    __syncthreads();
    float acc = lin1_b[d];
    #pragma unroll
    for (int k = 0; k < D; ++k) acc += buf0[k] * lin1_w[k * D + d];
    buf1[d] = fmaxf(acc, 0.f);
    __syncthreads();
    acc = fc_b[d];
    #pragma unroll
    for (int k = 0; k < D; ++k) acc += buf1[k] * fc_w[k * D + d];
    buf0[d] = fmaxf(acc, 0.f);
    __syncthreads();
    acc = fc_b[D + d];
    #pragma unroll
    for (int k = 0; k < D; ++k) acc += buf0[k] * fc_w[D * D + k * D + d];
    buf1[d] = fmaxf(acc, 0.f);
    __syncthreads();
    float v = buf1[d] * lin2_w[d];
    #pragma unroll
    for (int off = 32; off; off >>= 1) v += __shfl_down(v, off);
    if (d == 0) out[g] = v + lin2_b[0];
}

extern "C" void kernel_launch(void* const* d_in, const int* in_sizes, int n_in,
                              void* d_out, int out_size, void* d_ws, size_t ws_size,
                              hipStream_t stream) {
    const float* x      = (const float*)d_in[0];
    const int*   ei     = (const int*)  d_in[1];
    const float* ew     = (const float*)d_in[2];
    const int*   batch  = (const int*)  d_in[3];
    const float* lin0_w = (const float*)d_in[4];
    const float* lin0_b = (const float*)d_in[5];
    const float* conv_w = (const float*)d_in[6];
    const float* conv_b = (const float*)d_in[7];
    const float* lin1_w = (const float*)d_in[8];
    const float* lin1_b = (const float*)d_in[9];
    const float* fc_w   = (const float*)d_in[10];
    const float* fc_b   = (const float*)d_in[11];
    const float* lin2_w = (const float*)d_in[12];
    const float* lin2_b = (const float*)d_in[13];
    float* out = (float*)d_out;

    const int* rowv = ei;
    const int* colv = ei + NE;

    // workspace layout (~66 MB)
    float* bufA     = (float*)d_ws;                 // N*D
    float* bufB     = bufA + (size_t)NN * D;        // N*D
    int2*  csr      = (int2*)(bufB + (size_t)NN * D); // E (src, norm-bits)
    int*   rowstart = (int*)(csr + NE);             // N+1
    float* deg      = (float*)(rowstart + NN + 1);  // N (becomes dis in place)
    int*   counts   = (int*)(deg + NN);             // N
    int*   cursor   = counts + NN;                  // N
    int*   bsums    = cursor + NN;                  // 256
    float* pooled   = (float*)(bsums + 256);        // G*D
    float* cnt      = pooled + NG * D;              // G

    hipMemsetAsync(deg, 0, 3 * NN * sizeof(float), stream);          // deg+counts+cursor
    hipMemsetAsync(pooled, 0, (NG * D + NG) * sizeof(float), stream);

    k_degcnt<<<(NE + 255) / 256, 256, 0, stream>>>(colv, ew, deg, counts);
    k_dis<<<(NN + 255) / 256, 256, 0, stream>>>(deg);
    k_scan1<<<NB0, SCAN_T, 0, stream>>>(counts, rowstart, bsums);
    k_scan2<<<1, 256, 0, stream>>>(bsums);
    k_scan3<<<NB0, SCAN_T, 0, stream>>>(rowstart, bsums);
    k_fill<<<(NE + 255) / 256, 256, 0, stream>>>(rowv, colv, ew, deg, rowstart,
                                                 cursor, csr);

    k_lin0<<<NN / 16, 256, 0, stream>>>(x, lin0_w, lin0_b, bufA);

    k_conv<false><<<NN / 16, 256, 0, stream>>>(bufA, rowstart, csr,
                                               conv_w + 0 * D * D, conv_b + 0 * D,
                                               nullptr, bufB);
    k_conv<false><<<NN / 16, 256, 0, stream>>>(bufB, rowstart, csr,
                                               conv_w + 1 * D * D, conv_b + 1 * D,
                                               nullptr, bufA);
    k_conv<false><<<NN / 16, 256, 0, stream>>>(bufA, rowstart, csr,
                                               conv_w + 2 * D * D, conv_b + 2 * D,
                                               nullptr, bufB);
    k_cnt<<<(NN + 255) / 256, 256, 0, stream>>>(batch, cnt);
    k_conv<true><<<NN / 16, 256, 0, stream>>>(bufB, rowstart, csr,
                                              conv_w + 3 * D * D, conv_b + 3 * D,
                                              batch, pooled);

    k_head<<<NG, 64, 0, stream>>>(pooled, cnt, lin1_w, lin1_b, fc_w, fc_b,
                                  lin2_w, lin2_b, out);
}

// Round 4
// 665.894 us; speedup vs baseline: 3.0689x; 1.2925x over previous
//
#include <hip/hip_runtime.h>

#define NN 100000     // nodes
#define NE 1600000    // edges
#define FIN 100
#define D 64
#define NCONV 4
#define NG 500
#define SCAN_T 512
#define NB0 ((NN + SCAN_T - 1) / SCAN_T)   // 196

// ---------------- rank histogram: rank[e] = running count per dst ----------------
__global__ void k_rank(const int* __restrict__ col, int* __restrict__ counts,
                       int* __restrict__ rank) {
    int e = blockIdx.x * blockDim.x + threadIdx.x;
    if (e < NE) rank[e] = atomicAdd(&counts[col[e]], 1);
}

// ---------------- two-level exclusive scan of counts -> rowstart ----------------
__global__ __launch_bounds__(SCAN_T) void k_scan1(const int* __restrict__ counts,
                                                  int* __restrict__ rowstart,
                                                  int* __restrict__ bsums) {
    __shared__ int sh[SCAN_T];
    int t = threadIdx.x, i = blockIdx.x * SCAN_T + t;
    int v = (i < NN) ? counts[i] : 0;
    sh[t] = v;
    __syncthreads();
    for (int off = 1; off < SCAN_T; off <<= 1) {
        int u = (t >= off) ? sh[t - off] : 0;
        __syncthreads();
        sh[t] += u;
        __syncthreads();
    }
    if (i < NN) rowstart[i] = sh[t] - v;      // exclusive
    if (t == SCAN_T - 1) bsums[blockIdx.x] = sh[t];
}

__global__ __launch_bounds__(256) void k_scan2(int* __restrict__ bsums) {
    __shared__ int sh[256];
    int t = threadIdx.x;
    int v = (t < NB0) ? bsums[t] : 0;
    sh[t] = v;
    __syncthreads();
    for (int off = 1; off < 256; off <<= 1) {
        int u = (t >= off) ? sh[t - off] : 0;
        __syncthreads();
        sh[t] += u;
        __syncthreads();
    }
    if (t < NB0) bsums[t] = sh[t] - v;        // exclusive over block sums
}

__global__ __launch_bounds__(SCAN_T) void k_scan3(int* __restrict__ rowstart,
                                                  const int* __restrict__ bsums) {
    int i = blockIdx.x * SCAN_T + threadIdx.x;
    if (i < NN) rowstart[i] += bsums[blockIdx.x];
    if (i == 0) rowstart[NN] = NE;
}

// ---------------- CSR fill (no atomics): slot = rowstart[c] + rank[e] ----------
__global__ void k_fill(const int* __restrict__ row, const int* __restrict__ col,
                       const float* __restrict__ ew, const int* __restrict__ rank,
                       const int* __restrict__ rowstart, int2* __restrict__ csr) {
    int e = blockIdx.x * blockDim.x + threadIdx.x;
    if (e >= NE) return;
    int slot = rowstart[col[e]] + rank[e];
    csr[slot] = make_int2(row[e], __float_as_int(ew[e]));
}

// ---------------- per-node degree from CSR row sum -> dis = deg^{-1/2} --------
__global__ void k_rowdeg(const int2* __restrict__ csr, const int* __restrict__ rowstart,
                         float* __restrict__ dis) {
    int i = blockIdx.x * blockDim.x + threadIdx.x;
    if (i >= NN) return;
    int e0 = rowstart[i], e1 = rowstart[i + 1];
    float d = 0.f;
    for (int s = e0; s < e1; ++s) d += __int_as_float(csr[s].y);
    dis[i] = (d > 0.f) ? (1.0f / sqrtf(d)) : 0.f;
}

// ---------------- convert csr weight: ew -> dis[src]*ew*dis[dst] --------------
__global__ void k_rownorm(int2* __restrict__ csr, const int* __restrict__ rowstart,
                          const float* __restrict__ dis) {
    int i = blockIdx.x * blockDim.x + threadIdx.x;
    if (i >= NN) return;
    int e0 = rowstart[i], e1 = rowstart[i + 1];
    float dc = dis[i];
    for (int s = e0; s < e1; ++s) {
        int2 p = csr[s];
        float w = dis[p.x] * __int_as_float(p.y) * dc;
        csr[s].y = __float_as_int(w);
    }
}

// ---------------- lin0: out = relu(x @ W0 + b0), x [N,100], W0 [100,64] ----------
__global__ __launch_bounds__(256) void k_lin0(const float* __restrict__ x,
                                              const float* __restrict__ w,
                                              const float* __restrict__ b,
                                              float* __restrict__ out) {
    __shared__ float ws[FIN * D];     // 25.6 KB
    __shared__ float xs[16][FIN];     // 6.4 KB
    int t = threadIdx.x;
    for (int i = t; i < FIN * D; i += 256) ws[i] = w[i];
    int r0 = blockIdx.x * 16;
    for (int i = t; i < 16 * FIN; i += 256) {
        int rr = i / FIN, kk = i - rr * FIN;
        xs[rr][kk] = x[(r0 + rr) * FIN + kk];   // NN % 16 == 0
    }
    __syncthreads();
    int wave = t >> 6, lane = t & 63;
    float bv = b[lane];
    for (int ri = wave; ri < 16; ri += 4) {
        float acc = bv;
        #pragma unroll
        for (int k = 0; k < FIN; k += 4) {
            float4 xv = *reinterpret_cast<const float4*>(&xs[ri][k]);
            acc = fmaf(xv.x, ws[(k + 0) * D + lane], acc);
            acc = fmaf(xv.y, ws[(k + 1) * D + lane], acc);
            acc = fmaf(xv.z, ws[(k + 2) * D + lane], acc);
            acc = fmaf(xv.w, ws[(k + 3) * D + lane], acc);
        }
        out[(r0 + ri) * D + lane] = fmaxf(acc, 0.f);
    }
}

// ---------------- fused conv: CSR gather-aggregate + 64x64 matmul + bias + relu
// 16 nodes per block; one wave per node (4 nodes sequential per wave).
// Lane split: g = lane>>4 (edge subgroup), f = lane&15 (feature quad).
// 16 edges in flight per iteration via unconditional clamped loads.
__global__ __launch_bounds__(256) void k_conv(const float* __restrict__ src,
                                              const int* __restrict__ rowstart,
                                              const int2* __restrict__ csr,
                                              const float* __restrict__ w,
                                              const float* __restrict__ bias,
                                              float* __restrict__ dst) {
    __shared__ float ws[D * D];       // 16 KB
    __shared__ float row_lds[4][D];   // 1 KB, per-wave slot
    int t = threadIdx.x;
    for (int i = t; i < D * D; i += 256) ws[i] = w[i];
    __syncthreads();
    int wave = t >> 6, lane = t & 63;
    int g = lane >> 4;       // 0..3 edge subgroup
    int f = lane & 15;       // feature quad: features f*4 .. f*4+3
    int node0 = blockIdx.x * 16;
    float bv = bias[lane];
    for (int ni = wave; ni < 16; ni += 4) {
        int node = node0 + ni;                   // NN % 16 == 0, always valid
        int e0 = rowstart[node], e1 = rowstart[node + 1];
        float4 acc = {0.f, 0.f, 0.f, 0.f};
        for (int base = e0; base < e1; base += 16) {
            #pragma unroll
            for (int u = 0; u < 4; ++u) {
                int e = base + u * 4 + g;
                bool valid = (e < e1);
                int ee = valid ? e : e0;         // safe clamp (row non-empty here)
                int2 p = csr[ee];
                float wv = valid ? __int_as_float(p.y) : 0.f;
                float4 v = *reinterpret_cast<const float4*>(&src[p.x * D + f * 4]);
                acc.x = fmaf(v.x, wv, acc.x);
                acc.y = fmaf(v.y, wv, acc.y);
                acc.z = fmaf(v.z, wv, acc.z);
                acc.w = fmaf(v.w, wv, acc.w);
            }
        }
        // reduce across the 4 edge subgroups (lanes f, f+16, f+32, f+48)
        acc.x += __shfl_xor(acc.x, 16); acc.y += __shfl_xor(acc.y, 16);
        acc.z += __shfl_xor(acc.z, 16); acc.w += __shfl_xor(acc.w, 16);
        acc.x += __shfl_xor(acc.x, 32); acc.y += __shfl_xor(acc.y, 32);
        acc.z += __shfl_xor(acc.z, 32); acc.w += __shfl_xor(acc.w, 32);
        if (g == 0) *reinterpret_cast<float4*>(&row_lds[wave][f * 4]) = acc;
        // matmul: o[lane] = bias + sum_k row[k] * W[k][lane]  (LDS broadcast reads)
        float o = bv;
        #pragma unroll
        for (int k = 0; k < D; k += 4) {
            float4 r = *reinterpret_cast<const float4*>(&row_lds[wave][k]);
            o = fmaf(r.x, ws[(k + 0) * D + lane], o);
            o = fmaf(r.y, ws[(k + 1) * D + lane], o);
            o = fmaf(r.z, ws[(k + 2) * D + lane], o);
            o = fmaf(r.w, ws[(k + 3) * D + lane], o);
        }
        dst[node * D + lane] = fmaxf(o, 0.f);
    }
}

// ---------------- segmented mean-pool over sorted batch ----------------
// wave handles 16 consecutive nodes; flush one atomic set per graph-run.
__global__ __launch_bounds__(256) void k_pool(const float* __restrict__ src,
                                              const int* __restrict__ batch,
                                              float* __restrict__ pooled,
                                              float* __restrict__ cnt) {
    int wave = threadIdx.x >> 6, lane = threadIdx.x & 63;
    int n0 = blockIdx.x * 64 + wave * 16;
    float s = 0.f;
    int curg = -1, runlen = 0;
    for (int i = 0; i < 16; ++i) {
        int node = n0 + i;
        if (node >= NN) break;
        int gg = batch[node];
        if (gg != curg) {
            if (curg >= 0) {
                atomicAdd(&pooled[curg * D + lane], s);
                if (lane == 0) atomicAdd(&cnt[curg], (float)runlen);
            }
            curg = gg; s = 0.f; runlen = 0;
        }
        s += src[node * D + lane];
        ++runlen;
    }
    if (curg >= 0) {
        atomicAdd(&pooled[curg * D + lane], s);
        if (lane == 0) atomicAdd(&cnt[curg], (float)runlen);
    }
}

// ---------------- MLP head: one block per graph ----------------
__global__ __launch_bounds__(64) void k_head(const float* __restrict__ pooled,
                                             const float* __restrict__ cnt,
                                             const float* __restrict__ lin1_w,
                                             const float* __restrict__ lin1_b,
                                             const float* __restrict__ fc_w,
                                             const float* __restrict__ fc_b,
                                             const float* __restrict__ lin2_w,
                                             const float* __restrict__ lin2_b,
                                             float* __restrict__ out) {
    __shared__ float buf0[D], buf1[D];
    int g = blockIdx.x, d = threadIdx.x;
    float c = fmaxf(cnt[g], 1.0f);
    buf0[d] = pooled[g * D + d] / c;
    __syncthreads();
    float acc = lin1_b[d];
    #pragma unroll
    for (int k = 0; k < D; ++k) acc += buf0[k] * lin1_w[k * D + d];
    buf1[d] = fmaxf(acc, 0.f);
    __syncthreads();
    acc = fc_b[d];
    #pragma unroll
    for (int k = 0; k < D; ++k) acc += buf1[k] * fc_w[k * D + d];
    buf0[d] = fmaxf(acc, 0.f);
    __syncthreads();
    acc = fc_b[D + d];
    #pragma unroll
    for (int k = 0; k < D; ++k) acc += buf0[k] * fc_w[D * D + k * D + d];
    buf1[d] = fmaxf(acc, 0.f);
    __syncthreads();
    float v = buf1[d] * lin2_w[d];
    #pragma unroll
    for (int off = 32; off; off >>= 1) v += __shfl_down(v, off);
    if (d == 0) out[g] = v + lin2_b[0];
}

extern "C" void kernel_launch(void* const* d_in, const int* in_sizes, int n_in,
                              void* d_out, int out_size, void* d_ws, size_t ws_size,
                              hipStream_t stream) {
    const float* x      = (const float*)d_in[0];
    const int*   ei     = (const int*)  d_in[1];
    const float* ew     = (const float*)d_in[2];
    const int*   batch  = (const int*)  d_in[3];
    const float* lin0_w = (const float*)d_in[4];
    const float* lin0_b = (const float*)d_in[5];
    const float* conv_w = (const float*)d_in[6];
    const float* conv_b = (const float*)d_in[7];
    const float* lin1_w = (const float*)d_in[8];
    const float* lin1_b = (const float*)d_in[9];
    const float* fc_w   = (const float*)d_in[10];
    const float* fc_b   = (const float*)d_in[11];
    const float* lin2_w = (const float*)d_in[12];
    const float* lin2_b = (const float*)d_in[13];
    float* out = (float*)d_out;

    const int* rowv = ei;
    const int* colv = ei + NE;

    // workspace layout (~66 MB)
    float* bufA     = (float*)d_ws;                   // N*D
    float* bufB     = bufA + (size_t)NN * D;          // N*D
    int2*  csr      = (int2*)(bufB + (size_t)NN * D); // E (src, weight-bits)
    int*   rowstart = (int*)(csr + NE);               // N+1
    float* dis      = (float*)(rowstart + NN + 1);    // N
    int*   counts   = (int*)(dis + NN);               // N
    int*   bsums    = counts + NN;                    // 256
    float* pooled   = (float*)(bsums + 256);          // G*D
    float* cnt      = pooled + NG * D;                // G
    int*   rank     = (int*)bufB;                     // E, overlays bufB (dead until conv1)

    hipMemsetAsync(counts, 0, NN * sizeof(int), stream);
    hipMemsetAsync(pooled, 0, (NG * D + NG) * sizeof(float), stream);

    k_rank<<<(NE + 255) / 256, 256, 0, stream>>>(colv, counts, rank);
    k_scan1<<<NB0, SCAN_T, 0, stream>>>(counts, rowstart, bsums);
    k_scan2<<<1, 256, 0, stream>>>(bsums);
    k_scan3<<<NB0, SCAN_T, 0, stream>>>(rowstart, bsums);
    k_fill<<<(NE + 255) / 256, 256, 0, stream>>>(rowv, colv, ew, rank, rowstart, csr);
    k_rowdeg<<<(NN + 255) / 256, 256, 0, stream>>>(csr, rowstart, dis);
    k_rownorm<<<(NN + 255) / 256, 256, 0, stream>>>(csr, rowstart, dis);

    k_lin0<<<NN / 16, 256, 0, stream>>>(x, lin0_w, lin0_b, bufA);

    k_conv<<<NN / 16, 256, 0, stream>>>(bufA, rowstart, csr,
                                        conv_w + 0 * D * D, conv_b + 0 * D, bufB);
    k_conv<<<NN / 16, 256, 0, stream>>>(bufB, rowstart, csr,
                                        conv_w + 1 * D * D, conv_b + 1 * D, bufA);
    k_conv<<<NN / 16, 256, 0, stream>>>(bufA, rowstart, csr,
                                        conv_w + 2 * D * D, conv_b + 2 * D, bufB);
    k_conv<<<NN / 16, 256, 0, stream>>>(bufB, rowstart, csr,
                                        conv_w + 3 * D * D, conv_b + 3 * D, bufA);

    k_pool<<<(NN + 63) / 64, 256, 0, stream>>>(bufA, batch, pooled, cnt);
    k_head<<<NG, 64, 0, stream>>>(pooled, cnt, lin1_w, lin1_b, fc_w, fc_b,
                                  lin2_w, lin2_b, out);
}

// Round 5
// 655.128 us; speedup vs baseline: 3.1193x; 1.0164x over previous
//
#include <hip/hip_runtime.h>

#define NN 100000     // nodes
#define NE 1600000    // edges
#define FIN 100
#define D 64
#define NCONV 4
#define NG 500
#define SCAN_T 512
#define NB0 ((NN + SCAN_T - 1) / SCAN_T)   // 196

typedef unsigned int uint;
typedef unsigned short ushort;

// f32 -> bf16 round-to-nearest-even
__device__ inline ushort f2bf(float x) {
    uint u = __float_as_uint(x);
    u += 0x7fffu + ((u >> 16) & 1u);
    return (ushort)(u >> 16);
}
__device__ inline float bflo(uint u) { return __uint_as_float(u << 16); }
__device__ inline float bfhi(uint u) { return __uint_as_float(u & 0xffff0000u); }

// ---------------- rank histogram: rank[e] = running count per dst ----------------
__global__ void k_rank(const int* __restrict__ col, int* __restrict__ counts,
                       int* __restrict__ rank) {
    int e = blockIdx.x * blockDim.x + threadIdx.x;
    if (e < NE) rank[e] = atomicAdd(&counts[col[e]], 1);
}

// ---------------- two-level exclusive scan of counts -> rowstart ----------------
__global__ __launch_bounds__(SCAN_T) void k_scan1(const int* __restrict__ counts,
                                                  int* __restrict__ rowstart,
                                                  int* __restrict__ bsums) {
    __shared__ int sh[SCAN_T];
    int t = threadIdx.x, i = blockIdx.x * SCAN_T + t;
    int v = (i < NN) ? counts[i] : 0;
    sh[t] = v;
    __syncthreads();
    for (int off = 1; off < SCAN_T; off <<= 1) {
        int u = (t >= off) ? sh[t - off] : 0;
        __syncthreads();
        sh[t] += u;
        __syncthreads();
    }
    if (i < NN) rowstart[i] = sh[t] - v;      // exclusive
    if (t == SCAN_T - 1) bsums[blockIdx.x] = sh[t];
}

__global__ __launch_bounds__(256) void k_scan2(int* __restrict__ bsums) {
    __shared__ int sh[256];
    int t = threadIdx.x;
    int v = (t < NB0) ? bsums[t] : 0;
    sh[t] = v;
    __syncthreads();
    for (int off = 1; off < 256; off <<= 1) {
        int u = (t >= off) ? sh[t - off] : 0;
        __syncthreads();
        sh[t] += u;
        __syncthreads();
    }
    if (t < NB0) bsums[t] = sh[t] - v;        // exclusive over block sums
}

__global__ __launch_bounds__(SCAN_T) void k_scan3(int* __restrict__ rowstart,
                                                  const int* __restrict__ bsums) {
    int i = blockIdx.x * SCAN_T + threadIdx.x;
    if (i < NN) rowstart[i] += bsums[blockIdx.x];
    if (i == 0) rowstart[NN] = NE;
}

// ---------------- CSR fill (no atomics): slot = rowstart[c] + rank[e] ----------
__global__ void k_fill(const int* __restrict__ row, const int* __restrict__ col,
                       const float* __restrict__ ew, const int* __restrict__ rank,
                       const int* __restrict__ rowstart, int2* __restrict__ csr) {
    int e = blockIdx.x * blockDim.x + threadIdx.x;
    if (e >= NE) return;
    int slot = rowstart[col[e]] + rank[e];
    csr[slot] = make_int2(row[e], __float_as_int(ew[e]));
}

// ---------------- per-node degree from CSR row sum -> dis = deg^{-1/2} --------
__global__ void k_rowdeg(const int2* __restrict__ csr, const int* __restrict__ rowstart,
                         float* __restrict__ dis) {
    int i = blockIdx.x * blockDim.x + threadIdx.x;
    if (i >= NN) return;
    int e0 = rowstart[i], e1 = rowstart[i + 1];
    float d = 0.f;
    for (int s = e0; s < e1; ++s) d += __int_as_float(csr[s].y);
    dis[i] = (d > 0.f) ? (1.0f / sqrtf(d)) : 0.f;
}

// ---------------- convert csr weight: ew -> dis[src]*ew*dis[dst] --------------
__global__ void k_rownorm(int2* __restrict__ csr, const int* __restrict__ rowstart,
                          const float* __restrict__ dis) {
    int i = blockIdx.x * blockDim.x + threadIdx.x;
    if (i >= NN) return;
    int e0 = rowstart[i], e1 = rowstart[i + 1];
    float dc = dis[i];
    for (int s = e0; s < e1; ++s) {
        int2 p = csr[s];
        float w = dis[p.x] * __int_as_float(p.y) * dc;
        csr[s].y = __float_as_int(w);
    }
}

// ---------------- lin0: out = relu(x @ W0 + b0) -> bf16 rows ------------------
__global__ __launch_bounds__(256) void k_lin0(const float* __restrict__ x,
                                              const float* __restrict__ w,
                                              const float* __restrict__ b,
                                              ushort* __restrict__ out) {
    __shared__ float ws[FIN * D];     // 25.6 KB
    __shared__ float xs[16][FIN];     // 6.4 KB
    int t = threadIdx.x;
    for (int i = t; i < FIN * D; i += 256) ws[i] = w[i];
    int r0 = blockIdx.x * 16;
    for (int i = t; i < 16 * FIN; i += 256) {
        int rr = i / FIN, kk = i - rr * FIN;
        xs[rr][kk] = x[(r0 + rr) * FIN + kk];   // NN % 16 == 0
    }
    __syncthreads();
    int wave = t >> 6, lane = t & 63;
    float bv = b[lane];
    for (int ri = wave; ri < 16; ri += 4) {
        float acc = bv;
        #pragma unroll
        for (int k = 0; k < FIN; k += 4) {
            float4 xv = *reinterpret_cast<const float4*>(&xs[ri][k]);
            acc = fmaf(xv.x, ws[(k + 0) * D + lane], acc);
            acc = fmaf(xv.y, ws[(k + 1) * D + lane], acc);
            acc = fmaf(xv.z, ws[(k + 2) * D + lane], acc);
            acc = fmaf(xv.w, ws[(k + 3) * D + lane], acc);
        }
        out[(r0 + ri) * D + lane] = f2bf(fmaxf(acc, 0.f));
    }
}

// ---------------- fused conv: CSR gather(bf16 rows) + 64x64 matmul + bias + relu
// 16 nodes per block; one wave per node slot. g = lane>>4 edge subgroup,
// f = lane&15 feature quad. f32 accumulation throughout.
template <bool OUT_BF16>
__global__ __launch_bounds__(256) void k_conv(const ushort* __restrict__ src,
                                              const int* __restrict__ rowstart,
                                              const int2* __restrict__ csr,
                                              const float* __restrict__ w,
                                              const float* __restrict__ bias,
                                              void* __restrict__ dstv) {
    __shared__ float ws[D * D];       // 16 KB
    __shared__ float row_lds[4][D];   // 1 KB, per-wave slot
    int t = threadIdx.x;
    for (int i = t; i < D * D; i += 256) ws[i] = w[i];
    __syncthreads();
    int wave = t >> 6, lane = t & 63;
    int g = lane >> 4;       // 0..3 edge subgroup
    int f = lane & 15;       // feature quad: features f*4 .. f*4+3
    int node0 = blockIdx.x * 16;
    float bv = bias[lane];
    for (int ni = wave; ni < 16; ni += 4) {
        int node = node0 + ni;                   // NN % 16 == 0, always valid
        int e0 = rowstart[node], e1 = rowstart[node + 1];
        float4 acc = {0.f, 0.f, 0.f, 0.f};
        for (int base = e0; base < e1; base += 16) {
            #pragma unroll
            for (int u = 0; u < 4; ++u) {
                int e = base + u * 4 + g;
                bool valid = (e < e1);
                int ee = valid ? e : e0;         // safe clamp (row non-empty here)
                int2 p = csr[ee];
                float wv = valid ? __int_as_float(p.y) : 0.f;
                uint2 v = *reinterpret_cast<const uint2*>(&src[p.x * D + f * 4]);
                acc.x = fmaf(bflo(v.x), wv, acc.x);
                acc.y = fmaf(bfhi(v.x), wv, acc.y);
                acc.z = fmaf(bflo(v.y), wv, acc.z);
                acc.w = fmaf(bfhi(v.y), wv, acc.w);
            }
        }
        // reduce across the 4 edge subgroups (lanes f, f+16, f+32, f+48)
        acc.x += __shfl_xor(acc.x, 16); acc.y += __shfl_xor(acc.y, 16);
        acc.z += __shfl_xor(acc.z, 16); acc.w += __shfl_xor(acc.w, 16);
        acc.x += __shfl_xor(acc.x, 32); acc.y += __shfl_xor(acc.y, 32);
        acc.z += __shfl_xor(acc.z, 32); acc.w += __shfl_xor(acc.w, 32);
        if (g == 0) *reinterpret_cast<float4*>(&row_lds[wave][f * 4]) = acc;
        // matmul: o[lane] = bias + sum_k row[k] * W[k][lane]  (LDS broadcast reads)
        float o = bv;
        #pragma unroll
        for (int k = 0; k < D; k += 4) {
            float4 r = *reinterpret_cast<const float4*>(&row_lds[wave][k]);
            o = fmaf(r.x, ws[(k + 0) * D + lane], o);
            o = fmaf(r.y, ws[(k + 1) * D + lane], o);
            o = fmaf(r.z, ws[(k + 2) * D + lane], o);
            o = fmaf(r.w, ws[(k + 3) * D + lane], o);
        }
        o = fmaxf(o, 0.f);
        if (OUT_BF16) ((ushort*)dstv)[node * D + lane] = f2bf(o);
        else          ((float*)dstv)[node * D + lane] = o;
    }
}

// ---------------- segmented mean-pool over sorted batch (f32 src) -------------
__global__ __launch_bounds__(256) void k_pool(const float* __restrict__ src,
                                              const int* __restrict__ batch,
                                              float* __restrict__ pooled,
                                              float* __restrict__ cnt) {
    int wave = threadIdx.x >> 6, lane = threadIdx.x & 63;
    int n0 = blockIdx.x * 64 + wave * 16;
    float s = 0.f;
    int curg = -1, runlen = 0;
    for (int i = 0; i < 16; ++i) {
        int node = n0 + i;
        if (node >= NN) break;
        int gg = batch[node];
        if (gg != curg) {
            if (curg >= 0) {
                atomicAdd(&pooled[curg * D + lane], s);
                if (lane == 0) atomicAdd(&cnt[curg], (float)runlen);
            }
            curg = gg; s = 0.f; runlen = 0;
        }
        s += src[node * D + lane];
        ++runlen;
    }
    if (curg >= 0) {
        atomicAdd(&pooled[curg * D + lane], s);
        if (lane == 0) atomicAdd(&cnt[curg], (float)runlen);
    }
}

// ---------------- MLP head: one block per graph ----------------
__global__ __launch_bounds__(64) void k_head(const float* __restrict__ pooled,
                                             const float* __restrict__ cnt,
                                             const float* __restrict__ lin1_w,
                                             const float* __restrict__ lin1_b,
                                             const float* __restrict__ fc_w,
                                             const float* __restrict__ fc_b,
                                             const float* __restrict__ lin2_w,
                                             const float* __restrict__ lin2_b,
                                             float* __restrict__ out) {
    __shared__ float buf0[D], buf1[D];
    int g = blockIdx.x, d = threadIdx.x;
    float c = fmaxf(cnt[g], 1.0f);
    buf0[d] = pooled[g * D + d] / c;
    __syncthreads();
    float acc = lin1_b[d];
    #pragma unroll
    for (int k = 0; k < D; ++k) acc += buf0[k] * lin1_w[k * D + d];
    buf1[d] = fmaxf(acc, 0.f);
    __syncthreads();
    acc = fc_b[d];
    #pragma unroll
    for (int k = 0; k < D; ++k) acc += buf1[k] * fc_w[k * D + d];
    buf0[d] = fmaxf(acc, 0.f);
    __syncthreads();
    acc = fc_b[D + d];
    #pragma unroll
    for (int k = 0; k < D; ++k) acc += buf0[k] * fc_w[D * D + k * D + d];
    buf1[d] = fmaxf(acc, 0.f);
    __syncthreads();
    float v = buf1[d] * lin2_w[d];
    #pragma unroll
    for (int off = 32; off; off >>= 1) v += __shfl_down(v, off);
    if (d == 0) out[g] = v + lin2_b[0];
}

extern "C" void kernel_launch(void* const* d_in, const int* in_sizes, int n_in,
                              void* d_out, int out_size, void* d_ws, size_t ws_size,
                              hipStream_t stream) {
    const float* x      = (const float*)d_in[0];
    const int*   ei     = (const int*)  d_in[1];
    const float* ew     = (const float*)d_in[2];
    const int*   batch  = (const int*)  d_in[3];
    const float* lin0_w = (const float*)d_in[4];
    const float* lin0_b = (const float*)d_in[5];
    const float* conv_w = (const float*)d_in[6];
    const float* conv_b = (const float*)d_in[7];
    const float* lin1_w = (const float*)d_in[8];
    const float* lin1_b = (const float*)d_in[9];
    const float* fc_w   = (const float*)d_in[10];
    const float* fc_b   = (const float*)d_in[11];
    const float* lin2_w = (const float*)d_in[12];
    const float* lin2_b = (const float*)d_in[13];
    float* out = (float*)d_out;

    const int* rowv = ei;
    const int* colv = ei + NE;

    // workspace layout (~66 MB)
    ushort* bufA    = (ushort*)d_ws;                  // N*D bf16 (12.8 MB)
    ushort* bufB    = bufA + (size_t)NN * D;          // N*D bf16 (12.8 MB)
    float*  bufC    = (float*)(bufB + (size_t)NN * D);// N*D f32  (25.6 MB)
    int2*   csr     = (int2*)(bufC + (size_t)NN * D); // E (src, weight-bits)
    int*   rowstart = (int*)(csr + NE);               // N+1
    float* dis      = (float*)(rowstart + NN + 1);    // N
    int*   counts   = (int*)(dis + NN);               // N
    int*   bsums    = counts + NN;                    // 256
    float* pooled   = (float*)(bsums + 256);          // G*D
    float* cnt      = pooled + NG * D;                // G
    int*   rank     = (int*)bufC;                     // E, overlays bufC (dead until conv4)

    hipMemsetAsync(counts, 0, NN * sizeof(int), stream);
    hipMemsetAsync(pooled, 0, (NG * D + NG) * sizeof(float), stream);

    k_rank<<<(NE + 255) / 256, 256, 0, stream>>>(colv, counts, rank);
    k_scan1<<<NB0, SCAN_T, 0, stream>>>(counts, rowstart, bsums);
    k_scan2<<<1, 256, 0, stream>>>(bsums);
    k_scan3<<<NB0, SCAN_T, 0, stream>>>(rowstart, bsums);
    k_fill<<<(NE + 255) / 256, 256, 0, stream>>>(rowv, colv, ew, rank, rowstart, csr);
    k_rowdeg<<<(NN + 255) / 256, 256, 0, stream>>>(csr, rowstart, dis);
    k_rownorm<<<(NN + 255) / 256, 256, 0, stream>>>(csr, rowstart, dis);

    k_lin0<<<NN / 16, 256, 0, stream>>>(x, lin0_w, lin0_b, bufA);

    k_conv<true><<<NN / 16, 256, 0, stream>>>(bufA, rowstart, csr,
                                              conv_w + 0 * D * D, conv_b + 0 * D, bufB);
    k_conv<true><<<NN / 16, 256, 0, stream>>>(bufB, rowstart, csr,
                                              conv_w + 1 * D * D, conv_b + 1 * D, bufA);
    k_conv<true><<<NN / 16, 256, 0, stream>>>(bufA, rowstart, csr,
                                              conv_w + 2 * D * D, conv_b + 2 * D, bufB);
    k_conv<false><<<NN / 16, 256, 0, stream>>>(bufB, rowstart, csr,
                                               conv_w + 3 * D * D, conv_b + 3 * D, bufC);

    k_pool<<<(NN + 63) / 64, 256, 0, stream>>>(bufC, batch, pooled, cnt);
    k_head<<<NG, 64, 0, stream>>>(pooled, cnt, lin1_w, lin1_b, fc_w, fc_b,
                                  lin2_w, lin2_b, out);
}